// Round 4
// baseline (1257.963 us; speedup 1.0000x reference)
//
#include <hip/hip_runtime.h>
#include <hip/hip_bf16.h>
#include <cstdint>
#include <cstddef>

#define T_SEQ 2048
#define NH 16
#define DQK 192
#define DV 128

typedef __attribute__((ext_vector_type(8))) short short8;
typedef __attribute__((ext_vector_type(4))) float f32x4;

__device__ __forceinline__ void load_lds_16(const void* g, void* l) {
    __builtin_amdgcn_global_load_lds(
        (const __attribute__((address_space(1))) void*)g,
        (__attribute__((address_space(3))) void*)l, 16, 0, 0);
}

// ---------------------------------------------------------------------------
__global__ void cvt_pad(const float* __restrict__ in, __hip_bfloat16* __restrict__ out,
                        long n_real, long n_pad) {
    long i = ((long)blockIdx.x * blockDim.x + threadIdx.x) * 4;
    const long stride = (long)gridDim.x * blockDim.x * 4;
    for (; i < n_pad; i += stride) {
        float v0 = 0.f, v1 = 0.f, v2 = 0.f, v3 = 0.f;
        if (i < n_real) {
            const float4 v = *(const float4*)(in + i);
            v0 = v.x; v1 = v.y; v2 = v.z; v3 = v.w;
        }
        out[i + 0] = __float2bfloat16(v0);
        out[i + 1] = __float2bfloat16(v1);
        out[i + 2] = __float2bfloat16(v2);
        out[i + 3] = __float2bfloat16(v3);
    }
}

// ---------------------------------------------------------------------------
__global__ __launch_bounds__(256) void rmsnorm_bf16(
    const float* __restrict__ x, const float* __restrict__ w,
    __hip_bfloat16* __restrict__ y, int D, int ldx) {
    const int row = blockIdx.x;
    const float* xr = x + (size_t)row * ldx;
    float ss = 0.f;
    for (int i = threadIdx.x; i < D; i += 256) { float v = xr[i]; ss += v * v; }
    for (int off = 32; off > 0; off >>= 1) ss += __shfl_down(ss, off);
    __shared__ float part[4];
    if ((threadIdx.x & 63) == 0) part[threadIdx.x >> 6] = ss;
    __syncthreads();
    const float tot = part[0] + part[1] + part[2] + part[3];
    const float rs = rsqrtf(tot / (float)D + 1e-6f);
    __hip_bfloat16* yr = y + (size_t)row * D;
    for (int i = threadIdx.x; i < D; i += 256)
        yr[i] = __float2bfloat16(xr[i] * rs * w[i]);
}

// ---------------------------------------------------------------------------
// C[M,N] = A[M,K](bf16) @ B[Npad,K](bf16)^T, 128x128 tile, BK=32.
// Split-K via blockIdx.z: each z-slice covers K/gridDim.z contiguous k.
// EPI: 0 Cf=acc; 1 Cf=acc+Add; 2 Cb=silu(acc); 3 Cb*=acc; 4 atomicAdd(Cf,acc)
template<int EPI>
__global__ __launch_bounds__(256) void gemm_bt(
    const __hip_bfloat16* __restrict__ A, const __hip_bfloat16* __restrict__ B,
    float* __restrict__ Cf, __hip_bfloat16* __restrict__ Cb,
    const float* __restrict__ Add, int N, int K) {
    __shared__ __hip_bfloat16 As[128 * 32];
    __shared__ __hip_bfloat16 Bs[128 * 32];
    const int tid = threadIdx.x;
    const int wave = tid >> 6;
    const int lane = tid & 63;
    const int col = lane & 15;
    const int quad = lane >> 4;
    const long bm = (long)blockIdx.y * 128;
    const long bn = (long)blockIdx.x * 128;
    const int wm = (wave & 1) * 64;
    const int wn = (wave >> 1) * 64;
    const int ksub = K / gridDim.z;
    const int kbeg = blockIdx.z * ksub;
    const int kend = kbeg + ksub;

    const int f0 = tid * 8;
    const int r0 = f0 >> 5, c0 = f0 & 31;
    const int f1 = (256 + tid) * 8;
    const int r1 = f1 >> 5, c1 = f1 & 31;
    __hip_bfloat16* dstA0 = &As[wave * 512];
    __hip_bfloat16* dstA1 = &As[2048 + wave * 512];
    __hip_bfloat16* dstB0 = &Bs[wave * 512];
    __hip_bfloat16* dstB1 = &Bs[2048 + wave * 512];

    f32x4 acc[4][4];
    for (int i = 0; i < 4; i++)
        for (int j = 0; j < 4; j++) acc[i][j] = (f32x4){0.f, 0.f, 0.f, 0.f};

    for (int k0 = kbeg; k0 < kend; k0 += 32) {
        __syncthreads();
        load_lds_16(A + (bm + r0) * (long)K + k0 + c0, dstA0);
        load_lds_16(A + (bm + r1) * (long)K + k0 + c1, dstA1);
        load_lds_16(B + (bn + r0) * (long)K + k0 + c0, dstB0);
        load_lds_16(B + (bn + r1) * (long)K + k0 + c1, dstB1);
        __syncthreads();
        short8 a[4], b[4];
        for (int i = 0; i < 4; i++)
            a[i] = *(const short8*)&As[(wm + 16 * i + col) * 32 + quad * 8];
        for (int j = 0; j < 4; j++)
            b[j] = *(const short8*)&Bs[(wn + 16 * j + col) * 32 + quad * 8];
        for (int i = 0; i < 4; i++)
            for (int j = 0; j < 4; j++)
                acc[i][j] = __builtin_amdgcn_mfma_f32_16x16x32_bf16(a[i], b[j], acc[i][j], 0, 0, 0);
    }

    for (int i = 0; i < 4; i++) {
        const long gm = bm + wm + 16 * i + quad * 4;
        for (int j = 0; j < 4; j++) {
            const long gn = bn + wn + 16 * j + col;
            if (gn < N) {
                for (int r = 0; r < 4; r++) {
                    const long idx = (gm + r) * (long)N + gn;
                    const float a0 = acc[i][j][r];
                    if (EPI == 0) {
                        Cf[idx] = a0;
                    } else if (EPI == 1) {
                        Cf[idx] = a0 + Add[idx];
                    } else if (EPI == 2) {
                        const float s = a0 / (1.f + __expf(-a0));
                        Cb[idx] = __float2bfloat16(s);
                    } else if (EPI == 3) {
                        const float g = __bfloat162float(Cb[idx]);
                        Cb[idx] = __float2bfloat16(g * a0);
                    } else {
                        atomicAdd(&Cf[idx], a0);
                    }
                }
            }
        }
    }
}

// ---------------------------------------------------------------------------
// RoPE + repack: q_full bf16 [H][T][192], k_full bf16 [H][T][192], Vt bf16 [H][128][T]
__global__ __launch_bounds__(256) void rope_pack(
    const float* __restrict__ q, const float* __restrict__ ckv,
    const float* __restrict__ kv,
    const float* __restrict__ cosT, const float* __restrict__ sinT,
    __hip_bfloat16* __restrict__ qf, __hip_bfloat16* __restrict__ kf,
    __hip_bfloat16* __restrict__ vt) {
    const int t = blockIdx.x;
    const int tid = threadIdx.x;
    __shared__ float kemb[64];
    if (tid < 64) {
        const int j = tid;
        const int m = j & 31;
        const float c = cosT[t * 64 + j], s = sinT[t * 64 + j];
        const float x0 = ckv[(size_t)t * 576 + 512 + 2 * m];
        const float x1 = ckv[(size_t)t * 576 + 512 + 2 * m + 1];
        kemb[j] = (j >= 32) ? (x1 * c + x0 * s) : (x0 * c - x1 * s);
    }
    __syncthreads();
    for (int h = 0; h < NH; h++) {
        const size_t qrow = ((size_t)h * T_SEQ + t) * DQK;
        if (tid < 128) {
            qf[qrow + tid] = __float2bfloat16(q[(size_t)t * 3072 + h * DQK + tid]);
            kf[qrow + tid] = __float2bfloat16(kv[(size_t)t * 4096 + h * 256 + tid]);
            vt[((size_t)h * 128 + tid) * T_SEQ + t] =
                __float2bfloat16(kv[(size_t)t * 4096 + h * 256 + 128 + tid]);
        } else if (tid < 192) {
            const int j = tid - 128;
            const int m = j & 31;
            const float c = cosT[t * 64 + j], s = sinT[t * 64 + j];
            const float x0 = q[(size_t)t * 3072 + h * DQK + 128 + 2 * m];
            const float x1 = q[(size_t)t * 3072 + h * DQK + 128 + 2 * m + 1];
            const float v = (j >= 32) ? (x1 * c + x0 * s) : (x0 * c - x1 * s);
            qf[qrow + 128 + j] = __float2bfloat16(v);
            kf[qrow + 128 + j] = __float2bfloat16(kemb[j]);
        }
    }
}

// ---------------------------------------------------------------------------
#define KROW 208
#define VROW 80
#define PROW 72

__global__ __launch_bounds__(256) void flash_attn(
    const __hip_bfloat16* __restrict__ Qf, const __hip_bfloat16* __restrict__ Kf,
    const __hip_bfloat16* __restrict__ Vt, __hip_bfloat16* __restrict__ Oout) {
    const int h = blockIdx.y;
    const int qt = (h < 8) ? blockIdx.x : (31 - blockIdx.x);
    const int tid = threadIdx.x;
    const int wave = tid >> 6;
    const int lane = tid & 63;
    const int col = lane & 15;
    const int quad = lane >> 4;
    const int q0b = qt * 64;
    const int q0w = q0b + wave * 16;

    __shared__ __hip_bfloat16 Ks[1792 * 8];
    __shared__ __hip_bfloat16 Vs[128 * VROW];
    __shared__ __hip_bfloat16 Plds[4][16 * PROW];

    const __hip_bfloat16* Qh = Qf + (size_t)h * T_SEQ * DQK;
    const __hip_bfloat16* Kh = Kf + (size_t)h * T_SEQ * DQK;
    const __hip_bfloat16* Vh = Vt + (size_t)h * DV * T_SEQ;

    short8 qfr[6];
    for (int d = 0; d < 6; d++)
        qfr[d] = *(const short8*)&Qh[(size_t)(q0w + col) * DQK + d * 32 + quad * 8];

    float m_i[4], l_i[4];
    f32x4 o[8];
    for (int r = 0; r < 4; r++) { m_i[r] = -INFINITY; l_i[r] = 0.f; }
    for (int dt = 0; dt < 8; dt++) o[dt] = (f32x4){0.f, 0.f, 0.f, 0.f};

    const float scaling = 0.07216878364870323f;
    const int kc_end = q0b + 64;

    for (int kc = 0; kc < kc_end; kc += 64) {
        __syncthreads();
        #pragma unroll
        for (int it = 0; it < 7; it++) {
            const int L = (it * 256 + tid) * 16;
            const int row = L / 416;
            const int c16 = (L % 416) / 16;
            const __hip_bfloat16* src = (row < 64 && c16 < 24)
                ? Kh + (size_t)(kc + row) * DQK + c16 * 8 : Kh;
            load_lds_16(src, (char*)Ks + it * 4096 + wave * 1024);
        }
        #pragma unroll
        for (int it = 0; it < 5; it++) {
            const int L = (it * 256 + tid) * 16;
            const int row = L / 160;
            const int c16 = (L % 160) / 16;
            const __hip_bfloat16* src = (c16 < 8)
                ? Vh + (size_t)row * T_SEQ + kc + c16 * 8 : Vh;
            load_lds_16(src, (char*)Vs + it * 4096 + wave * 1024);
        }
        __syncthreads();

        f32x4 s[4];
        for (int f = 0; f < 4; f++) s[f] = (f32x4){0.f, 0.f, 0.f, 0.f};
        for (int d = 0; d < 6; d++)
            for (int f = 0; f < 4; f++) {
                short8 b = *(const short8*)&Ks[(f * 16 + col) * KROW + d * 32 + quad * 8];
                s[f] = __builtin_amdgcn_mfma_f32_16x16x32_bf16(qfr[d], b, s[f], 0, 0, 0);
            }

        float mx[4];
        for (int r = 0; r < 4; r++) mx[r] = -1e30f;
        for (int f = 0; f < 4; f++)
            for (int r = 0; r < 4; r++) {
                const int rowq = q0w + quad * 4 + r;
                const int kcol = kc + f * 16 + col;
                float v = s[f][r] * scaling;
                if (kcol > rowq) v = -1e30f;
                s[f][r] = v;
                mx[r] = fmaxf(mx[r], v);
            }
        for (int off = 1; off < 16; off <<= 1)
            for (int r = 0; r < 4; r++)
                mx[r] = fmaxf(mx[r], __shfl_xor(mx[r], off));
        float alpha[4], rsum[4];
        for (int r = 0; r < 4; r++) {
            const float mnew = fmaxf(m_i[r], mx[r]);
            alpha[r] = __expf(m_i[r] - mnew);
            m_i[r] = mnew;
            rsum[r] = 0.f;
        }
        float p[4][4];
        for (int f = 0; f < 4; f++)
            for (int r = 0; r < 4; r++) {
                p[f][r] = __expf(s[f][r] - m_i[r]);
                rsum[r] += p[f][r];
            }
        for (int off = 1; off < 16; off <<= 1)
            for (int r = 0; r < 4; r++)
                rsum[r] += __shfl_xor(rsum[r], off);
        for (int r = 0; r < 4; r++) l_i[r] = l_i[r] * alpha[r] + rsum[r];
        for (int dt = 0; dt < 8; dt++)
            for (int r = 0; r < 4; r++) o[dt][r] *= alpha[r];

        for (int f = 0; f < 4; f++)
            for (int r = 0; r < 4; r++)
                Plds[wave][(quad * 4 + r) * PROW + f * 16 + col] = __float2bfloat16(p[f][r]);
        asm volatile("s_waitcnt lgkmcnt(0)" ::: "memory");
        short8 pa[2];
        for (int c = 0; c < 2; c++)
            pa[c] = *(const short8*)&Plds[wave][col * PROW + c * 32 + quad * 8];

        for (int dt = 0; dt < 8; dt++)
            for (int c = 0; c < 2; c++) {
                short8 bv = *(const short8*)&Vs[(dt * 16 + col) * VROW + c * 32 + quad * 8];
                o[dt] = __builtin_amdgcn_mfma_f32_16x16x32_bf16(pa[c], bv, o[dt], 0, 0, 0);
            }
    }

    for (int r = 0; r < 4; r++) {
        const int row = q0w + quad * 4 + r;
        const float inv = 1.f / l_i[r];
        for (int dt = 0; dt < 8; dt++)
            Oout[(size_t)row * (NH * DV) + h * DV + dt * 16 + col] =
                __float2bfloat16(o[dt][r] * inv);
    }
}

// ---------------------------------------------------------------------------
__global__ void fill_f32(float* __restrict__ y, long n, float v) {
    long i = (long)blockIdx.x * blockDim.x + threadIdx.x;
    const long st = (long)gridDim.x * blockDim.x;
    for (; i < n; i += st) y[i] = v;
}

// ---------------------------------------------------------------------------
extern "C" void kernel_launch(void* const* d_in, const int* in_sizes, int n_in,
                              void* d_out, int out_size, void* d_ws, size_t ws_size,
                              hipStream_t stream) {
    const float* hidden   = (const float*)d_in[0];
    const float* cosT     = (const float*)d_in[1];
    const float* sinT     = (const float*)d_in[2];
    const float* ln_input = (const float*)d_in[3];
    const float* w_q_a    = (const float*)d_in[4];
    const float* ln_q_a   = (const float*)d_in[5];
    const float* w_q_b    = (const float*)d_in[6];
    const float* w_kv_a   = (const float*)d_in[7];
    const float* ln_kv_a  = (const float*)d_in[8];
    const float* w_kv_b   = (const float*)d_in[9];
    const float* w_o      = (const float*)d_in[10];
    const float* ln_post  = (const float*)d_in[11];
    const float* w_gate   = (const float*)d_in[12];
    const float* w_up     = (const float*)d_in[13];
    const float* w_down   = (const float*)d_in[14];
    float* out = (float*)d_out;

    char* ws = (char*)d_ws;
    size_t off = 0;
    auto alloc = [&](size_t bytes) -> char* {
        off = (off + 255) & ~(size_t)255;
        char* p = ws + off;
        off += bytes;
        return p;
    };

    char* W_ = alloc(11008l * 2048 * 2);
    char* A_ = alloc(2048l * 3072 * 4);
    char* B_ = alloc(2048l * 10944 * 2);
    char* C_ = alloc(2048l * 576 * 4);
    char* D_ = alloc(2048l * 2048 * 4);
    char* E_ = alloc((16l * 2048 * 192 + 16l * 128 * 2048) * 2);

    if (off > ws_size) {
        fill_f32<<<2048, 256, 0, stream>>>(out, (long)out_size, -77777.0f);
        return;
    }

    auto* Wb     = (__hip_bfloat16*)W_;
    auto* h_b    = (__hip_bfloat16*)A_;
    auto* q_f    = (float*)A_;
    auto* attn_b = (__hip_bfloat16*)A_;
    auto* h2_b   = (__hip_bfloat16*)A_;
    auto* qa_f   = (float*)B_;
    auto* kv_f   = (float*)B_;
    auto* gate_b = (__hip_bfloat16*)B_;
    auto* ckv_f  = (float*)C_;
    auto* qan_b  = (__hip_bfloat16*)D_;
    auto* ckvn_b = (__hip_bfloat16*)(D_ + 2048l * 1536 * 2);
    auto* kf_b   = (__hip_bfloat16*)D_;
    auto* res_f  = (float*)D_;
    auto* qf_b   = (__hip_bfloat16*)E_;
    auto* vt_b   = (__hip_bfloat16*)(E_ + 16l * 2048 * 192 * 2);

    auto cvt = [&](const float* src, long n_real, long n_pad) {
        cvt_pad<<<2048, 256, 0, stream>>>(src, Wb, n_real, n_pad);
    };
    auto gemm = [&](int EPI, const __hip_bfloat16* A, float* Cf, __hip_bfloat16* Cb,
                    const float* Add, int N, int Npad, int K, int splits) {
        dim3 g(Npad / 128, 16, splits);
        if (EPI == 0)      gemm_bt<0><<<g, 256, 0, stream>>>(A, Wb, Cf, Cb, Add, N, K);
        else if (EPI == 1) gemm_bt<1><<<g, 256, 0, stream>>>(A, Wb, Cf, Cb, Add, N, K);
        else if (EPI == 2) gemm_bt<2><<<g, 256, 0, stream>>>(A, Wb, Cf, Cb, Add, N, K);
        else if (EPI == 3) gemm_bt<3><<<g, 256, 0, stream>>>(A, Wb, Cf, Cb, Add, N, K);
        else               gemm_bt<4><<<g, 256, 0, stream>>>(A, Wb, Cf, Cb, Add, N, K);
    };
    auto zero = [&](float* p, long n) {
        fill_f32<<<2048, 256, 0, stream>>>(p, n, 0.f);
    };

    // attention pipeline
    rmsnorm_bf16<<<2048, 256, 0, stream>>>(hidden, ln_input, h_b, 2048, 2048);
    cvt(w_q_a, 1536l * 2048, 1536l * 2048);
    zero(qa_f, 2048l * 1536);
    gemm(4, h_b, qa_f, nullptr, nullptr, 1536, 1536, 2048, 4);       // 768 blocks
    cvt(w_kv_a, 576l * 2048, 640l * 2048);
    zero(ckv_f, 2048l * 576);
    gemm(4, h_b, ckv_f, nullptr, nullptr, 576, 640, 2048, 8);        // 640 blocks
    rmsnorm_bf16<<<2048, 256, 0, stream>>>(qa_f, ln_q_a, qan_b, 1536, 1536);
    rmsnorm_bf16<<<2048, 256, 0, stream>>>(ckv_f, ln_kv_a, ckvn_b, 512, 576);
    cvt(w_q_b, 3072l * 1536, 3072l * 1536);
    zero(q_f, 2048l * 3072);
    gemm(4, qan_b, q_f, nullptr, nullptr, 3072, 3072, 1536, 2);      // 768 blocks
    cvt(w_kv_b, 4096l * 512, 4096l * 512);
    zero(kv_f, 2048l * 4096);
    gemm(4, ckvn_b, kv_f, nullptr, nullptr, 4096, 4096, 512, 2);     // 1024 blocks
    rope_pack<<<2048, 256, 0, stream>>>(q_f, ckv_f, kv_f, cosT, sinT, qf_b, kf_b, vt_b);
    flash_attn<<<dim3(32, 16), 256, 0, stream>>>(qf_b, kf_b, vt_b, attn_b);
    cvt(w_o, 2048l * 2048, 2048l * 2048);
    hipMemcpyAsync(res_f, hidden, 2048l * 2048 * 4, hipMemcpyDeviceToDevice, stream);
    gemm(4, attn_b, res_f, nullptr, nullptr, 2048, 2048, 2048, 4);   // 1024 blocks

    // MLP
    rmsnorm_bf16<<<2048, 256, 0, stream>>>(res_f, ln_post, h2_b, 2048, 2048);
    cvt(w_gate, 10944l * 2048, 11008l * 2048);
    gemm(2, h2_b, nullptr, gate_b, nullptr, 10944, 11008, 2048, 1);  // 1376 blocks
    cvt(w_up, 10944l * 2048, 11008l * 2048);
    gemm(3, h2_b, nullptr, gate_b, nullptr, 10944, 11008, 2048, 1);  // 1376 blocks
    cvt(w_down, 2048l * 10944, 2048l * 10944);
    hipMemcpyAsync(out, res_f, 2048l * 2048 * 4, hipMemcpyDeviceToDevice, stream);
    gemm(4, gate_b, out, nullptr, nullptr, 2048, 2048, 10944, 6);    // 1536 blocks
}

// Round 5
// 1075.491 us; speedup vs baseline: 1.1697x; 1.1697x over previous
//
#include <hip/hip_runtime.h>
#include <hip/hip_bf16.h>
#include <cstdint>
#include <cstddef>

#define T_SEQ 2048
#define NH 16
#define DQK 192
#define DV 128

typedef __attribute__((ext_vector_type(8))) short short8;
typedef __attribute__((ext_vector_type(4))) float f32x4;

__device__ __forceinline__ void load_lds_16(const void* g, void* l) {
    __builtin_amdgcn_global_load_lds(
        (const __attribute__((address_space(1))) void*)g,
        (__attribute__((address_space(3))) void*)l, 16, 0, 0);
}

// ---------------------------------------------------------------------------
__global__ void cvt_pad(const float* __restrict__ in, __hip_bfloat16* __restrict__ out,
                        long n_real, long n_pad) {
    long i = ((long)blockIdx.x * blockDim.x + threadIdx.x) * 4;
    const long stride = (long)gridDim.x * blockDim.x * 4;
    for (; i < n_pad; i += stride) {
        float v0 = 0.f, v1 = 0.f, v2 = 0.f, v3 = 0.f;
        if (i < n_real) {
            const float4 v = *(const float4*)(in + i);
            v0 = v.x; v1 = v.y; v2 = v.z; v3 = v.w;
        }
        out[i + 0] = __float2bfloat16(v0);
        out[i + 1] = __float2bfloat16(v1);
        out[i + 2] = __float2bfloat16(v2);
        out[i + 3] = __float2bfloat16(v3);
    }
}

// ---------------------------------------------------------------------------
// Interleaved gate/up weight pack for fused GU GEMM.
// out: 11008 rows x 2048 bf16. Row R: group=R/32, pos=R%32;
// logical row ll = group*16 + (pos&15); src = pos<16 ? g : u; rows >= 5472 zero.
__global__ __launch_bounds__(256) void cvt_gu(
    const float* __restrict__ g, const float* __restrict__ u,
    __hip_bfloat16* __restrict__ out, int row_off) {
    const int R = blockIdx.x;
    const int group = R >> 5, pos = R & 31;
    const int ll = group * 16 + (pos & 15);
    const bool valid = ll < 5472;
    const float* src = (pos < 16) ? g : u;
    const float* srow = src + (size_t)(row_off + ll) * 2048;
    __hip_bfloat16* orow = out + (size_t)R * 2048;
    const int i0 = threadIdx.x * 8;
    float4 a = {0, 0, 0, 0}, b = {0, 0, 0, 0};
    if (valid) {
        a = *(const float4*)(srow + i0);
        b = *(const float4*)(srow + i0 + 4);
    }
    orow[i0 + 0] = __float2bfloat16(a.x); orow[i0 + 1] = __float2bfloat16(a.y);
    orow[i0 + 2] = __float2bfloat16(a.z); orow[i0 + 3] = __float2bfloat16(a.w);
    orow[i0 + 4] = __float2bfloat16(b.x); orow[i0 + 5] = __float2bfloat16(b.y);
    orow[i0 + 6] = __float2bfloat16(b.z); orow[i0 + 7] = __float2bfloat16(b.w);
}

// ---------------------------------------------------------------------------
__global__ __launch_bounds__(256) void rmsnorm_bf16(
    const float* __restrict__ x, const float* __restrict__ w,
    __hip_bfloat16* __restrict__ y, int D, int ldx) {
    const int row = blockIdx.x;
    const float* xr = x + (size_t)row * ldx;
    float ss = 0.f;
    for (int i = threadIdx.x; i < D; i += 256) { float v = xr[i]; ss += v * v; }
    for (int off = 32; off > 0; off >>= 1) ss += __shfl_down(ss, off);
    __shared__ float part[4];
    if ((threadIdx.x & 63) == 0) part[threadIdx.x >> 6] = ss;
    __syncthreads();
    const float tot = part[0] + part[1] + part[2] + part[3];
    const float rs = rsqrtf(tot / (float)D + 1e-6f);
    __hip_bfloat16* yr = y + (size_t)row * D;
    for (int i = threadIdx.x; i < D; i += 256)
        yr[i] = __float2bfloat16(xr[i] * rs * w[i]);
}

// ---------------------------------------------------------------------------
// dst = (base ? base : 0) + sum_z parts[z*pstride + i]
__global__ void reduce_parts(const float* __restrict__ parts, long pstride, int np,
                             const float* __restrict__ base, float* __restrict__ dst,
                             long n) {
    long i = ((long)blockIdx.x * blockDim.x + threadIdx.x) * 4;
    const long st = (long)gridDim.x * blockDim.x * 4;
    for (; i < n; i += st) {
        float4 acc = base ? *(const float4*)(base + i) : (float4){0, 0, 0, 0};
        for (int z = 0; z < np; z++) {
            const float4 p = *(const float4*)(parts + z * pstride + i);
            acc.x += p.x; acc.y += p.y; acc.z += p.z; acc.w += p.w;
        }
        *(float4*)(dst + i) = acc;
    }
}

// ---------------------------------------------------------------------------
// C = A[M,K](bf16) @ B[Npad,K](bf16)^T, 128x128 tile, BK=32, split-K via z.
// EPI 0: Cf[z*pstride + idx] = acc   (partial buffers; np=gridDim.z)
// EPI 5: fused gate-up: B rows interleaved 16g/16u; Cb[row*ldc + gn] =
//        bf16(silu(g)*u) with gn logical (per-half), guard gn < N.
template<int EPI>
__global__ __launch_bounds__(256) void gemm_bt(
    const __hip_bfloat16* __restrict__ A, const __hip_bfloat16* __restrict__ B,
    float* __restrict__ Cf, __hip_bfloat16* __restrict__ Cb,
    int N, int K, int ldc, long pstride) {
    __shared__ __hip_bfloat16 As[128 * 32];
    __shared__ __hip_bfloat16 Bs[128 * 32];
    const int tid = threadIdx.x;
    const int wave = tid >> 6;
    const int lane = tid & 63;
    const int col = lane & 15;
    const int quad = lane >> 4;
    const long bm = (long)blockIdx.y * 128;
    const long bn = (long)blockIdx.x * 128;
    const int wm = (wave & 1) * 64;
    const int wn = (wave >> 1) * 64;
    const int ksub = K / gridDim.z;
    const int kbeg = blockIdx.z * ksub;
    const int kend = kbeg + ksub;

    const int f0 = tid * 8;
    const int r0 = f0 >> 5, c0 = f0 & 31;
    const int f1 = (256 + tid) * 8;
    const int r1 = f1 >> 5, c1 = f1 & 31;
    __hip_bfloat16* dstA0 = &As[wave * 512];
    __hip_bfloat16* dstA1 = &As[2048 + wave * 512];
    __hip_bfloat16* dstB0 = &Bs[wave * 512];
    __hip_bfloat16* dstB1 = &Bs[2048 + wave * 512];

    f32x4 acc[4][4];
    for (int i = 0; i < 4; i++)
        for (int j = 0; j < 4; j++) acc[i][j] = (f32x4){0.f, 0.f, 0.f, 0.f};

    for (int k0 = kbeg; k0 < kend; k0 += 32) {
        __syncthreads();
        load_lds_16(A + (bm + r0) * (long)K + k0 + c0, dstA0);
        load_lds_16(A + (bm + r1) * (long)K + k0 + c1, dstA1);
        load_lds_16(B + (bn + r0) * (long)K + k0 + c0, dstB0);
        load_lds_16(B + (bn + r1) * (long)K + k0 + c1, dstB1);
        __syncthreads();
        short8 a[4], b[4];
        for (int i = 0; i < 4; i++)
            a[i] = *(const short8*)&As[(wm + 16 * i + col) * 32 + quad * 8];
        for (int j = 0; j < 4; j++)
            b[j] = *(const short8*)&Bs[(wn + 16 * j + col) * 32 + quad * 8];
        for (int i = 0; i < 4; i++)
            for (int j = 0; j < 4; j++)
                acc[i][j] = __builtin_amdgcn_mfma_f32_16x16x32_bf16(a[i], b[j], acc[i][j], 0, 0, 0);
    }

    if (EPI == 0) {
        float* Cz = Cf + (long)blockIdx.z * pstride;
        for (int i = 0; i < 4; i++) {
            const long gm = bm + wm + 16 * i + quad * 4;
            for (int j = 0; j < 4; j++) {
                const long gn = bn + wn + 16 * j + col;
                if (gn < N)
                    for (int r = 0; r < 4; r++)
                        Cz[(gm + r) * (long)ldc + gn] = acc[i][j][r];
            }
        }
    } else { // EPI 5
        for (int i = 0; i < 4; i++) {
            const long gm = bm + wm + 16 * i + quad * 4;
            for (int jp = 0; jp < 2; jp++) {
                const long gn = (((bn + wn) >> 5) + jp) * 16 + col; // logical col
                if (gn < N) {
                    for (int r = 0; r < 4; r++) {
                        const float g = acc[i][2 * jp][r];
                        const float u = acc[i][2 * jp + 1][r];
                        const float s = g / (1.f + __expf(-g));
                        Cb[(gm + r) * (long)ldc + gn] = __float2bfloat16(s * u);
                    }
                }
            }
        }
    }
}

// ---------------------------------------------------------------------------
__global__ __launch_bounds__(256) void rope_pack(
    const float* __restrict__ q, const float* __restrict__ ckv,
    const float* __restrict__ kv,
    const float* __restrict__ cosT, const float* __restrict__ sinT,
    __hip_bfloat16* __restrict__ qf, __hip_bfloat16* __restrict__ kf,
    __hip_bfloat16* __restrict__ vt) {
    const int t = blockIdx.x;
    const int tid = threadIdx.x;
    __shared__ float kemb[64];
    if (tid < 64) {
        const int j = tid;
        const int m = j & 31;
        const float c = cosT[t * 64 + j], s = sinT[t * 64 + j];
        const float x0 = ckv[(size_t)t * 576 + 512 + 2 * m];
        const float x1 = ckv[(size_t)t * 576 + 512 + 2 * m + 1];
        kemb[j] = (j >= 32) ? (x1 * c + x0 * s) : (x0 * c - x1 * s);
    }
    __syncthreads();
    for (int h = 0; h < NH; h++) {
        const size_t qrow = ((size_t)h * T_SEQ + t) * DQK;
        if (tid < 128) {
            qf[qrow + tid] = __float2bfloat16(q[(size_t)t * 3072 + h * DQK + tid]);
            kf[qrow + tid] = __float2bfloat16(kv[(size_t)t * 4096 + h * 256 + tid]);
            vt[((size_t)h * 128 + tid) * T_SEQ + t] =
                __float2bfloat16(kv[(size_t)t * 4096 + h * 256 + 128 + tid]);
        } else if (tid < 192) {
            const int j = tid - 128;
            const int m = j & 31;
            const float c = cosT[t * 64 + j], s = sinT[t * 64 + j];
            const float x0 = q[(size_t)t * 3072 + h * DQK + 128 + 2 * m];
            const float x1 = q[(size_t)t * 3072 + h * DQK + 128 + 2 * m + 1];
            const float v = (j >= 32) ? (x1 * c + x0 * s) : (x0 * c - x1 * s);
            qf[qrow + 128 + j] = __float2bfloat16(v);
            kf[qrow + 128 + j] = __float2bfloat16(kemb[j]);
        }
    }
}

// ---------------------------------------------------------------------------
#define KROW 208
#define VROW 80
#define PROW 72

__global__ __launch_bounds__(256) void flash_attn(
    const __hip_bfloat16* __restrict__ Qf, const __hip_bfloat16* __restrict__ Kf,
    const __hip_bfloat16* __restrict__ Vt, __hip_bfloat16* __restrict__ Oout) {
    const int h = blockIdx.y;
    const int qt = (h < 8) ? blockIdx.x : (31 - blockIdx.x);
    const int tid = threadIdx.x;
    const int wave = tid >> 6;
    const int lane = tid & 63;
    const int col = lane & 15;
    const int quad = lane >> 4;
    const int q0b = qt * 64;
    const int q0w = q0b + wave * 16;

    __shared__ __hip_bfloat16 Ks[1792 * 8];
    __shared__ __hip_bfloat16 Vs[128 * VROW];
    __shared__ __hip_bfloat16 Plds[4][16 * PROW];

    const __hip_bfloat16* Qh = Qf + (size_t)h * T_SEQ * DQK;
    const __hip_bfloat16* Kh = Kf + (size_t)h * T_SEQ * DQK;
    const __hip_bfloat16* Vh = Vt + (size_t)h * DV * T_SEQ;

    short8 qfr[6];
    for (int d = 0; d < 6; d++)
        qfr[d] = *(const short8*)&Qh[(size_t)(q0w + col) * DQK + d * 32 + quad * 8];

    float m_i[4], l_i[4];
    f32x4 o[8];
    for (int r = 0; r < 4; r++) { m_i[r] = -INFINITY; l_i[r] = 0.f; }
    for (int dt = 0; dt < 8; dt++) o[dt] = (f32x4){0.f, 0.f, 0.f, 0.f};

    const float scaling = 0.07216878364870323f;
    const int kc_end = q0b + 64;

    for (int kc = 0; kc < kc_end; kc += 64) {
        __syncthreads();
        #pragma unroll
        for (int it = 0; it < 7; it++) {
            const int L = (it * 256 + tid) * 16;
            const int row = L / 416;
            const int c16 = (L % 416) / 16;
            const __hip_bfloat16* src = (row < 64 && c16 < 24)
                ? Kh + (size_t)(kc + row) * DQK + c16 * 8 : Kh;
            load_lds_16(src, (char*)Ks + it * 4096 + wave * 1024);
        }
        #pragma unroll
        for (int it = 0; it < 5; it++) {
            const int L = (it * 256 + tid) * 16;
            const int row = L / 160;
            const int c16 = (L % 160) / 16;
            const __hip_bfloat16* src = (c16 < 8)
                ? Vh + (size_t)row * T_SEQ + kc + c16 * 8 : Vh;
            load_lds_16(src, (char*)Vs + it * 4096 + wave * 1024);
        }
        __syncthreads();

        f32x4 s[4];
        for (int f = 0; f < 4; f++) s[f] = (f32x4){0.f, 0.f, 0.f, 0.f};
        for (int d = 0; d < 6; d++)
            for (int f = 0; f < 4; f++) {
                short8 b = *(const short8*)&Ks[(f * 16 + col) * KROW + d * 32 + quad * 8];
                s[f] = __builtin_amdgcn_mfma_f32_16x16x32_bf16(qfr[d], b, s[f], 0, 0, 0);
            }

        float mx[4];
        for (int r = 0; r < 4; r++) mx[r] = -1e30f;
        for (int f = 0; f < 4; f++)
            for (int r = 0; r < 4; r++) {
                const int rowq = q0w + quad * 4 + r;
                const int kcol = kc + f * 16 + col;
                float v = s[f][r] * scaling;
                if (kcol > rowq) v = -1e30f;
                s[f][r] = v;
                mx[r] = fmaxf(mx[r], v);
            }
        for (int off = 1; off < 16; off <<= 1)
            for (int r = 0; r < 4; r++)
                mx[r] = fmaxf(mx[r], __shfl_xor(mx[r], off));
        float alpha[4], rsum[4];
        for (int r = 0; r < 4; r++) {
            const float mnew = fmaxf(m_i[r], mx[r]);
            alpha[r] = __expf(m_i[r] - mnew);
            m_i[r] = mnew;
            rsum[r] = 0.f;
        }
        float p[4][4];
        for (int f = 0; f < 4; f++)
            for (int r = 0; r < 4; r++) {
                p[f][r] = __expf(s[f][r] - m_i[r]);
                rsum[r] += p[f][r];
            }
        for (int off = 1; off < 16; off <<= 1)
            for (int r = 0; r < 4; r++)
                rsum[r] += __shfl_xor(rsum[r], off);
        for (int r = 0; r < 4; r++) l_i[r] = l_i[r] * alpha[r] + rsum[r];
        for (int dt = 0; dt < 8; dt++)
            for (int r = 0; r < 4; r++) o[dt][r] *= alpha[r];

        for (int f = 0; f < 4; f++)
            for (int r = 0; r < 4; r++)
                Plds[wave][(quad * 4 + r) * PROW + f * 16 + col] = __float2bfloat16(p[f][r]);
        asm volatile("s_waitcnt lgkmcnt(0)" ::: "memory");
        short8 pa[2];
        for (int c = 0; c < 2; c++)
            pa[c] = *(const short8*)&Plds[wave][col * PROW + c * 32 + quad * 8];

        for (int dt = 0; dt < 8; dt++)
            for (int c = 0; c < 2; c++) {
                short8 bv = *(const short8*)&Vs[(dt * 16 + col) * VROW + c * 32 + quad * 8];
                o[dt] = __builtin_amdgcn_mfma_f32_16x16x32_bf16(pa[c], bv, o[dt], 0, 0, 0);
            }
    }

    for (int r = 0; r < 4; r++) {
        const int row = q0w + quad * 4 + r;
        const float inv = 1.f / l_i[r];
        for (int dt = 0; dt < 8; dt++)
            Oout[(size_t)row * (NH * DV) + h * DV + dt * 16 + col] =
                __float2bfloat16(o[dt][r] * inv);
    }
}

// ---------------------------------------------------------------------------
__global__ void fill_f32(float* __restrict__ y, long n, float v) {
    long i = (long)blockIdx.x * blockDim.x + threadIdx.x;
    const long st = (long)gridDim.x * blockDim.x;
    for (; i < n; i += st) y[i] = v;
}

// ---------------------------------------------------------------------------
extern "C" void kernel_launch(void* const* d_in, const int* in_sizes, int n_in,
                              void* d_out, int out_size, void* d_ws, size_t ws_size,
                              hipStream_t stream) {
    const float* hidden   = (const float*)d_in[0];
    const float* cosT     = (const float*)d_in[1];
    const float* sinT     = (const float*)d_in[2];
    const float* ln_input = (const float*)d_in[3];
    const float* w_q_a    = (const float*)d_in[4];
    const float* ln_q_a   = (const float*)d_in[5];
    const float* w_q_b    = (const float*)d_in[6];
    const float* w_kv_a   = (const float*)d_in[7];
    const float* ln_kv_a  = (const float*)d_in[8];
    const float* w_kv_b   = (const float*)d_in[9];
    const float* w_o      = (const float*)d_in[10];
    const float* ln_post  = (const float*)d_in[11];
    const float* w_gate   = (const float*)d_in[12];
    const float* w_up     = (const float*)d_in[13];
    const float* w_down   = (const float*)d_in[14];
    float* out = (float*)d_out;

    char* ws = (char*)d_ws;
    size_t off = 0;
    auto alloc = [&](size_t bytes) -> char* {
        off = (off + 255) & ~(size_t)255;
        char* p = ws + off;
        off += bytes;
        return p;
    };

    // Regions (peak ~166 MB), lifetime-aliased:
    char* W_ = alloc(11008l * 2048 * 2);   // weights bf16 (serial reuse)
    char* A_ = alloc(2048l * 2048 * 4 * 2);// h_b/q_f/attn_b/h2_b -> down parts(2)
    char* B_ = alloc(2048l * 10944 * 2);   // qa_f | kva parts -> kv_f -> o parts -> act_b
    char* C_ = alloc(2048l * 576 * 4);     // ckv_f
    char* D_ = alloc(2048l * 2048 * 4);    // qan+ckvn -> kf -> res_f
    char* E_ = alloc((16l * 2048 * 192 + 16l * 128 * 2048) * 2); // qf + vt

    if (off > ws_size) {
        fill_f32<<<2048, 256, 0, stream>>>(out, (long)out_size, -77777.0f);
        return;
    }

    auto* Wb       = (__hip_bfloat16*)W_;
    auto* h_b      = (__hip_bfloat16*)A_;
    auto* q_f      = (float*)A_;
    auto* attn_b   = (__hip_bfloat16*)A_;
    auto* h2_b     = (__hip_bfloat16*)A_;
    auto* dn_parts = (float*)A_;
    auto* qa_f     = (float*)B_;
    auto* kva_parts= (float*)(B_ + (1l << 24));  // +16.78 MB (past qa_f)
    auto* kv_f     = (float*)B_;
    auto* o_parts  = (float*)B_;
    auto* act_b    = (__hip_bfloat16*)B_;
    auto* ckv_f    = (float*)C_;
    auto* qan_b    = (__hip_bfloat16*)D_;
    auto* ckvn_b   = (__hip_bfloat16*)(D_ + 2048l * 1536 * 2);
    auto* kf_b     = (__hip_bfloat16*)D_;
    auto* res_f    = (float*)D_;
    auto* qf_b     = (__hip_bfloat16*)E_;
    auto* vt_b     = (__hip_bfloat16*)(E_ + 16l * 2048 * 192 * 2);

    auto cvt = [&](const float* src, long n_real, long n_pad) {
        cvt_pad<<<2048, 256, 0, stream>>>(src, Wb, n_real, n_pad);
    };
    auto gemm0 = [&](const __hip_bfloat16* A, float* Cf, int N, int Npad, int K,
                     int splits, long pstride) {
        dim3 g(Npad / 128, 16, splits);
        gemm_bt<0><<<g, 256, 0, stream>>>(A, Wb, Cf, nullptr, N, K, N, pstride);
    };

    // ---- attention pipeline ----
    rmsnorm_bf16<<<2048, 256, 0, stream>>>(hidden, ln_input, h_b, 2048, 2048);
    cvt(w_q_a, 1536l * 2048, 1536l * 2048);
    gemm0(h_b, qa_f, 1536, 1536, 2048, 1, 0);                        // 192 blocks
    cvt(w_kv_a, 576l * 2048, 640l * 2048);
    gemm0(h_b, kva_parts, 576, 640, 2048, 4, 2048l * 576);           // 320 blocks
    reduce_parts<<<2048, 256, 0, stream>>>(kva_parts, 2048l * 576, 4, nullptr,
                                           ckv_f, 2048l * 576);
    rmsnorm_bf16<<<2048, 256, 0, stream>>>(qa_f, ln_q_a, qan_b, 1536, 1536);
    rmsnorm_bf16<<<2048, 256, 0, stream>>>(ckv_f, ln_kv_a, ckvn_b, 512, 576);
    cvt(w_q_b, 3072l * 1536, 3072l * 1536);
    gemm0(qan_b, q_f, 3072, 3072, 1536, 1, 0);                       // 384 blocks
    cvt(w_kv_b, 4096l * 512, 4096l * 512);
    gemm0(ckvn_b, kv_f, 4096, 4096, 512, 1, 0);                      // 512 blocks
    rope_pack<<<2048, 256, 0, stream>>>(q_f, ckv_f, kv_f, cosT, sinT, qf_b, kf_b, vt_b);
    flash_attn<<<dim3(32, 16), 256, 0, stream>>>(qf_b, kf_b, vt_b, attn_b);
    cvt(w_o, 2048l * 2048, 2048l * 2048);
    gemm0(attn_b, o_parts, 2048, 2048, 2048, 2, 2048l * 2048);       // 512 blocks
    reduce_parts<<<2048, 256, 0, stream>>>(o_parts, 2048l * 2048, 2, hidden,
                                           res_f, 2048l * 2048);     // res = hidden + o

    // ---- MLP ----
    rmsnorm_bf16<<<2048, 256, 0, stream>>>(res_f, ln_post, h2_b, 2048, 2048);
    for (int half = 0; half < 2; half++) {
        cvt_gu<<<11008, 256, 0, stream>>>(w_gate, w_up, Wb, half * 5472);
        dim3 g(86, 16, 1);
        gemm_bt<5><<<g, 256, 0, stream>>>(h2_b, Wb, nullptr,
                                          act_b + half * 5472, 5472, 2048, 10944, 0);
    }
    cvt(w_down, 2048l * 10944, 2048l * 10944);
    gemm0(act_b, dn_parts, 2048, 2048, 10944, 2, 2048l * 2048);      // 512 blocks
    reduce_parts<<<2048, 256, 0, stream>>>(dn_parts, 2048l * 2048, 2, res_f,
                                           out, 2048l * 2048);       // out = res + down
}